// Round 1
// baseline (285.601 us; speedup 1.0000x reference)
//
#include <hip/hip_runtime.h>
#include <hip/hip_bf16.h>

// Problem constants
#define S_LEN   2048
#define BATCH   2
#define NH      16
#define DH      64
#define DMODEL  1024
#define MTOT    (BATCH * S_LEN)   // 4096

typedef __attribute__((ext_vector_type(4))) float f32x4;
typedef __attribute__((ext_vector_type(8))) short s16x8;   // 8 bf16
typedef __attribute__((ext_vector_type(4))) short s16x4;

#define MFMA_BF16(a, b, c) __builtin_amdgcn_mfma_f32_16x16x32_bf16((a), (b), (c), 0, 0, 0)

static __device__ __forceinline__ short f2bf(float f) {
    // round-to-nearest-even fp32 -> bf16
    union { float f; unsigned u; } v; v.f = f;
    unsigned r = v.u + 0x7fffu + ((v.u >> 16) & 1u);
    return (short)(r >> 16);
}

// ---------------------------------------------------------------------------
// Prep 1: W[k][n] fp32 -> Wt[n][k] bf16 (transposed, so GEMM B-staging is
// k-contiguous 16B loads, same as A). grid (16,16,4): z selects wq/wk/wv/wo.
// ---------------------------------------------------------------------------
__global__ __launch_bounds__(256) void prep_wt(const float* __restrict__ wq,
                                               const float* __restrict__ wk,
                                               const float* __restrict__ wv,
                                               const float* __restrict__ wo,
                                               short* __restrict__ wtb) {
    const float* W = (blockIdx.z == 0) ? wq : (blockIdx.z == 1) ? wk
                   : (blockIdx.z == 2) ? wv : wo;
    short* out = wtb + (size_t)blockIdx.z * DMODEL * DMODEL;

    __shared__ short T[64][72];   // 72-short stride: 8B-aligned rows, odd-ish banks
    const int t  = threadIdx.x;
    const int k0 = blockIdx.y * 64, n0 = blockIdx.x * 64;

    #pragma unroll
    for (int p = 0; p < 4; ++p) {
        const int kk = p * 16 + (t >> 4);
        const int nn = (t & 15) * 4;
        f32x4 v = *(const f32x4*)(W + (size_t)(k0 + kk) * DMODEL + n0 + nn);
        #pragma unroll
        for (int j = 0; j < 4; ++j) T[nn + j][kk] = f2bf(v[j]);
    }
    __syncthreads();
    #pragma unroll
    for (int p = 0; p < 4; ++p) {
        const int nn = p * 16 + (t >> 4);
        const int kk = (t & 15) * 4;
        *(s16x4*)(out + (size_t)(n0 + nn) * DMODEL + k0 + kk) = *(const s16x4*)&T[nn][kk];
    }
}

// ---------------------------------------------------------------------------
// Prep 2: x fp32 -> bf16 (vectorized)
// ---------------------------------------------------------------------------
__global__ __launch_bounds__(256) void prep_x(const float* __restrict__ x,
                                              short* __restrict__ xb) {
    const size_t i = (size_t)(blockIdx.x * 256 + threadIdx.x) * 8;
    f32x4 a = *(const f32x4*)(x + i);
    f32x4 b = *(const f32x4*)(x + i + 4);
    s16x8 o;
    #pragma unroll
    for (int j = 0; j < 4; ++j) { o[j] = f2bf(a[j]); o[4 + j] = f2bf(b[j]); }
    *(s16x8*)(xb + i) = o;
}

// ---------------------------------------------------------------------------
// Prep 3: RoPE tables cos/sin [2048][32] fp32
// ---------------------------------------------------------------------------
__global__ __launch_bounds__(256) void prep_rope(float* __restrict__ cosT,
                                                 float* __restrict__ sinT) {
    const int idx = blockIdx.x * 256 + threadIdx.x;   // 65536 total
    const int s = idx >> 5, i = idx & 31;
    // inv_freq = 10000^(-i/32) = 2^(-i/32 * log2(10000))
    const float inv = exp2f(-(float)i * (13.287712379549449f / 32.0f));
    const float ang = (float)s * inv;
    cosT[idx] = cosf(ang);
    sinT[idx] = sinf(ang);
}

// ---------------------------------------------------------------------------
// Shared 128x128 GEMM mainloop. A[m][k] bf16, Bt[n][k] bf16 (both k-major).
// 4 waves (2x2), each 64x64 via 4x4 frags of mfma_f32_16x16x32_bf16.
// ---------------------------------------------------------------------------
__device__ __forceinline__ void gemm_tile_128(const short* __restrict__ A,
                                              const short* __restrict__ Bt,
                                              f32x4 acc[4][4]) {
    __shared__ short As[128][40];   // 40-short stride: 16B-aligned rows, ~2-way banks
    __shared__ short Bs[128][40];
    const int t    = threadIdx.x;
    const int lane = t & 63;
    const int wave = t >> 6;
    const int wm   = (wave >> 1) * 64;
    const int wn   = (wave & 1) * 64;
    const int g    = lane >> 4, c16 = lane & 15;
    const int m0   = blockIdx.y * 128;
    const int n0   = blockIdx.x * 128;
    const int srow = t >> 2;          // 0..63
    const int sk8  = (t & 3) * 8;     // 0,8,16,24

    for (int k0 = 0; k0 < DMODEL; k0 += 32) {
        #pragma unroll
        for (int p = 0; p < 2; ++p) {
            s16x8 va = *(const s16x8*)(A  + (size_t)(m0 + p * 64 + srow) * DMODEL + k0 + sk8);
            *(s16x8*)&As[p * 64 + srow][sk8] = va;
            s16x8 vb = *(const s16x8*)(Bt + (size_t)(n0 + p * 64 + srow) * DMODEL + k0 + sk8);
            *(s16x8*)&Bs[p * 64 + srow][sk8] = vb;
        }
        __syncthreads();
        s16x8 af[4], bfr[4];
        #pragma unroll
        for (int i = 0; i < 4; ++i) {
            af[i]  = *(const s16x8*)&As[wm + i * 16 + c16][g * 8];
            bfr[i] = *(const s16x8*)&Bs[wn + i * 16 + c16][g * 8];
        }
        #pragma unroll
        for (int i = 0; i < 4; ++i)
            #pragma unroll
            for (int j = 0; j < 4; ++j)
                acc[i][j] = MFMA_BF16(af[i], bfr[j], acc[i][j]);
        __syncthreads();
    }
}

// ---------------------------------------------------------------------------
// QKV GEMM + fused RoPE epilogue. grid (8,32,3): z=0 Q(rope), 1 K(rope), 2 V.
// Output layout [B][H][S][DH] bf16.
// C/D frag mapping (verified m89): col = lane&15, row = (lane>>4)*4 + reg.
// RoPE pair (2i,2i+1) lives in adjacent cols -> adjacent lanes -> shfl_xor(1).
// ---------------------------------------------------------------------------
__global__ __launch_bounds__(256) void gemm_qkv(const short* __restrict__ xb,
                                                const short* __restrict__ wtb,
                                                short* __restrict__ Qo,
                                                short* __restrict__ Ko,
                                                short* __restrict__ Vo,
                                                const float* __restrict__ cosT,
                                                const float* __restrict__ sinT) {
    const int z = blockIdx.z;
    const short* Bt = wtb + (size_t)z * DMODEL * DMODEL;
    short* out = (z == 0) ? Qo : (z == 1) ? Ko : Vo;

    f32x4 acc[4][4] = {};
    gemm_tile_128(xb, Bt, acc);

    const int t    = threadIdx.x;
    const int lane = t & 63;
    const int wave = t >> 6;
    const int wm   = (wave >> 1) * 64, wn = (wave & 1) * 64;
    const int g    = lane >> 4, c16 = lane & 15;
    const int m0   = blockIdx.y * 128, n0 = blockIdx.x * 128;
    const bool dorope = (z < 2);

    #pragma unroll
    for (int j = 0; j < 4; ++j) {
        const int n = n0 + wn + j * 16 + c16;
        const int h = n >> 6, d = n & 63;
        #pragma unroll
        for (int i = 0; i < 4; ++i) {
            #pragma unroll
            for (int r = 0; r < 4; ++r) {
                const int m = m0 + wm + i * 16 + g * 4 + r;
                const int s = m & (S_LEN - 1);
                const int b = m >> 11;
                float v = acc[i][j][r];
                float res = v;
                if (dorope) {
                    float vo = __shfl_xor(v, 1, 64);   // partner col = n^1
                    float cs = cosT[s * 32 + (d >> 1)];
                    float sn = sinT[s * 32 + (d >> 1)];
                    res = (d & 1) ? (vo * sn + v * cs) : (v * cs - vo * sn);
                }
                out[(((size_t)b * NH + h) * S_LEN + s) * DH + d] = f2bf(res);
            }
        }
    }
}

// ---------------------------------------------------------------------------
// Causal flash attention. 1 wave per block, 16 q-rows per wave, KV tile = 32.
// Q/K/V layout [B*H][S][64] bf16. Output [B][S][H*64] bf16 (ready for O-proj).
// QK^T: A=Q (row=lane&15, k=(lane>>4)*8+j contiguous), B=K row reads.
// P repacked through LDS to form the PV A-fragment.
// ---------------------------------------------------------------------------
__global__ __launch_bounds__(64) void attn(const short* __restrict__ Q,
                                           const short* __restrict__ K,
                                           const short* __restrict__ V,
                                           short* __restrict__ O) {
    const int lane = threadIdx.x;
    const int g = lane >> 4, c16 = lane & 15;
    const int q0 = blockIdx.x * 16;
    const int bh = blockIdx.y;                    // b*16 + h
    const size_t base = (size_t)bh * S_LEN * DH;

    __shared__ short P[16][40];                   // P[q_local][kv_local]

    s16x8 aq0 = *(const s16x8*)(Q + base + (size_t)(q0 + c16) * DH + g * 8);
    s16x8 aq1 = *(const s16x8*)(Q + base + (size_t)(q0 + c16) * DH + 32 + g * 8);

    f32x4 o[4] = {};
    float mrun[4] = {-1e30f, -1e30f, -1e30f, -1e30f};
    float lrun[4] = {};

    const int kv_end = q0 + 15;
    for (int kv0 = 0; kv0 <= kv_end; kv0 += 32) {
        const short* kp0 = K + base + (size_t)(kv0 + c16) * DH;
        const short* kp1 = K + base + (size_t)(kv0 + 16 + c16) * DH;
        s16x8 kf00 = *(const s16x8*)(kp0 + g * 8);
        s16x8 kf10 = *(const s16x8*)(kp0 + 32 + g * 8);
        s16x8 kf01 = *(const s16x8*)(kp1 + g * 8);
        s16x8 kf11 = *(const s16x8*)(kp1 + 32 + g * 8);

        f32x4 s0 = {}, s1 = {};
        s0 = MFMA_BF16(aq0, kf00, s0);
        s0 = MFMA_BF16(aq1, kf10, s0);
        s1 = MFMA_BF16(aq0, kf01, s1);
        s1 = MFMA_BF16(aq1, kf11, s1);

        // online softmax; C rows = q_local (lane>>4)*4+r, cols = kv_local lane&15
        #pragma unroll
        for (int r = 0; r < 4; ++r) {
            const int qrow = q0 + g * 4 + r;
            float v0 = s0[r] * 0.125f; if (kv0 + c16 > qrow)      v0 = -1e30f;
            float v1 = s1[r] * 0.125f; if (kv0 + 16 + c16 > qrow) v1 = -1e30f;
            float tm = fmaxf(v0, v1);
            tm = fmaxf(tm, __shfl_xor(tm, 1, 64));
            tm = fmaxf(tm, __shfl_xor(tm, 2, 64));
            tm = fmaxf(tm, __shfl_xor(tm, 4, 64));
            tm = fmaxf(tm, __shfl_xor(tm, 8, 64));
            const float mn = fmaxf(mrun[r], tm);
            const float corr = __expf(mrun[r] - mn);
            mrun[r] = mn;
            const float p0 = __expf(v0 - mn);
            const float p1 = __expf(v1 - mn);
            float rs = p0 + p1;
            rs += __shfl_xor(rs, 1, 64);
            rs += __shfl_xor(rs, 2, 64);
            rs += __shfl_xor(rs, 4, 64);
            rs += __shfl_xor(rs, 8, 64);
            lrun[r] = lrun[r] * corr + rs;
            #pragma unroll
            for (int nt = 0; nt < 4; ++nt) o[nt][r] *= corr;
            P[g * 4 + r][c16]      = f2bf(p0);
            P[g * 4 + r][c16 + 16] = f2bf(p1);
        }
        // same-wave LDS RAW: DS pipe is in-order per wave; fence for safety
        asm volatile("s_waitcnt lgkmcnt(0)" ::: "memory");
        s16x8 ap = *(const s16x8*)&P[c16][g * 8];

        #pragma unroll
        for (int nt = 0; nt < 4; ++nt) {
            const short* vp = V + base + (size_t)(kv0 + g * 8) * DH + nt * 16 + c16;
            s16x8 vf;
            #pragma unroll
            for (int j = 0; j < 8; ++j) vf[j] = vp[(size_t)j * DH];
            o[nt] = MFMA_BF16(ap, vf, o[nt]);
        }
    }

    const int b = bh >> 4, h = bh & 15;
    #pragma unroll
    for (int nt = 0; nt < 4; ++nt)
        #pragma unroll
        for (int r = 0; r < 4; ++r) {
            const float val = o[nt][r] / lrun[r];
            O[((size_t)(b * S_LEN + q0 + g * 4 + r)) * DMODEL + h * DH + nt * 16 + c16] = f2bf(val);
        }
}

// ---------------------------------------------------------------------------
// Output projection: C = Ob(bf16) @ wo, fp32 out.
// ---------------------------------------------------------------------------
__global__ __launch_bounds__(256) void gemm_o(const short* __restrict__ Ob,
                                              const short* __restrict__ WoT,
                                              float* __restrict__ C) {
    f32x4 acc[4][4] = {};
    gemm_tile_128(Ob, WoT, acc);

    const int t    = threadIdx.x;
    const int lane = t & 63;
    const int wave = t >> 6;
    const int wm   = (wave >> 1) * 64, wn = (wave & 1) * 64;
    const int g    = lane >> 4, c16 = lane & 15;
    const int m0   = blockIdx.y * 128, n0 = blockIdx.x * 128;

    #pragma unroll
    for (int i = 0; i < 4; ++i)
        #pragma unroll
        for (int j = 0; j < 4; ++j) {
            const int n = n0 + wn + j * 16 + c16;
            #pragma unroll
            for (int r = 0; r < 4; ++r) {
                const int m = m0 + wm + i * 16 + g * 4 + r;
                C[(size_t)m * DMODEL + n] = acc[i][j][r];
            }
        }
}

// ---------------------------------------------------------------------------
extern "C" void kernel_launch(void* const* d_in, const int* in_sizes, int n_in,
                              void* d_out, int out_size, void* d_ws, size_t ws_size,
                              hipStream_t stream) {
    const float* x  = (const float*)d_in[0];
    const float* wq = (const float*)d_in[1];
    const float* wk = (const float*)d_in[2];
    const float* wv = (const float*)d_in[3];
    const float* wo = (const float*)d_in[4];
    float* out = (float*)d_out;

    char* ws = (char*)d_ws;
    // layout (bytes): wtb 8MB | xb 8MB | cos 256KB | sin 256KB (pad to 1MB) |
    //                 Qb 8MB | Kb 8MB | Vb 8MB | Ob 8MB   => 49MB total
    short* wtb  = (short*)ws;                              // [4][1024][1024] bf16
    short* xb   = (short*)(ws + (8ull  << 20));            // [4096][1024] bf16
    float* cosT = (float*)(ws + (16ull << 20));            // [2048][32]
    float* sinT = (float*)(ws + (16ull << 20) + (256ull << 10));
    short* Qb   = (short*)(ws + (17ull << 20));            // [B*H][S][64] bf16
    short* Kb   = (short*)(ws + (25ull << 20));
    short* Vb   = (short*)(ws + (33ull << 20));
    short* Ob   = (short*)(ws + (41ull << 20));            // [4096][1024] bf16

    prep_wt  <<<dim3(16, 16, 4), 256, 0, stream>>>(wq, wk, wv, wo, wtb);
    prep_x   <<<dim3(2048),      256, 0, stream>>>(x, xb);
    prep_rope<<<dim3(256),       256, 0, stream>>>(cosT, sinT);

    gemm_qkv<<<dim3(8, 32, 3), 256, 0, stream>>>(xb, wtb, Qb, Kb, Vb, cosT, sinT);
    attn    <<<dim3(128, 32),   64, 0, stream>>>(Qb, Kb, Vb, Ob);
    gemm_o  <<<dim3(8, 32),    256, 0, stream>>>(Ob, wtb + 3ull * DMODEL * DMODEL, out);
}